// Round 3
// baseline (194.018 us; speedup 1.0000x reference)
//
#include <hip/hip_runtime.h>

#define LSEQ 256
#define DMODEL 512
#define NHEAD 8
#define DKH 64
#define BATCH 4

#define TWO_LOG2E 2.885390081777927f

using short8 = __attribute__((ext_vector_type(8))) short;
using f32x4  = __attribute__((ext_vector_type(4))) float;

// split fp32 -> truncated bf16 hi + bf16(lo remainder)
__device__ __forceinline__ void split4(const float* f, ushort4& h, ushort4& l) {
  unsigned short hh[4], ll[4];
#pragma unroll
  for (int j = 0; j < 4; ++j) {
    unsigned int u = __float_as_uint(f[j]);
    hh[j] = (unsigned short)(u >> 16);
    float hf = __uint_as_float(u & 0xFFFF0000u);
    ll[j] = (unsigned short)(__float_as_uint(f[j] - hf) >> 16);
  }
  h = make_ushort4(hh[0], hh[1], hh[2], hh[3]);
  l = make_ushort4(ll[0], ll[1], ll[2], ll[3]);
}

// ---------------------------------------------------------------------------
// prep: z=0..2 -> convert X (q,k,v) to bf16 hi/lo [z][1024][512]
//       z=3..6 -> convert+transpose W (Wq,Wk,Wv,W0) to [g][n][k] hi/lo
//                 (Wq,Wk prescaled by 2*log2e so attn exp2 needs no multiply)
// ---------------------------------------------------------------------------
__global__ __launch_bounds__(256) void prep_kernel(
    const float* __restrict__ q, const float* __restrict__ k, const float* __restrict__ v,
    const float* __restrict__ Wq, const float* __restrict__ Wk,
    const float* __restrict__ Wv, const float* __restrict__ W0,
    unsigned short* __restrict__ xhi, unsigned short* __restrict__ xlo,
    unsigned short* __restrict__ whi, unsigned short* __restrict__ wlo)
{
  const int z = blockIdx.z;
  const int tid = threadIdx.x;
  if (z < 3) {
    const float* X = (z == 0) ? q : (z == 1) ? k : v;
    const int r = blockIdx.x * 32 + (tid >> 3);
    const int c = blockIdx.y * 32 + ((tid & 7) << 2);
    float4 f = *(const float4*)&X[r * DMODEL + c];
    ushort4 h4, l4;
    split4((const float*)&f, h4, l4);
    const int base = (z * 1024 + r) * DMODEL + c;
    *(ushort4*)&xhi[base] = h4;
    *(ushort4*)&xlo[base] = l4;
  } else {
    if (blockIdx.x >= 16) return;
    const int g = z - 3;
    const float* W = (g == 0) ? Wq : (g == 1) ? Wk : (g == 2) ? Wv : W0;
    const float scale = (g < 2) ? TWO_LOG2E : 1.0f;
    const int k0 = blockIdx.x * 32, n0 = blockIdx.y * 32;
    __shared__ float tile[32][36];
    {
      const int r = tid >> 3, c = (tid & 7) << 2;
      float4 f = *(const float4*)&W[(k0 + r) * DMODEL + n0 + c];
      tile[r][c + 0] = f.x * scale;
      tile[r][c + 1] = f.y * scale;
      tile[r][c + 2] = f.z * scale;
      tile[r][c + 3] = f.w * scale;
    }
    __syncthreads();
    const int n = tid >> 3, kk = (tid & 7) << 2;
    float x[4];
#pragma unroll
    for (int j = 0; j < 4; ++j) x[j] = tile[kk + j][n];
    ushort4 h4, l4;
    split4(x, h4, l4);
    const int base = (g * DMODEL + n0 + n) * DMODEL + k0 + kk;
    *(ushort4*)&whi[base] = h4;
    *(ushort4*)&wlo[base] = l4;
  }
}

// ---------------------------------------------------------------------------
// bf16-split MFMA GEMM: C(1024,512) = X(1024,512) @ W(512,512) + bscale*bias
// xh/xl: [1024][512] bf16 hi/lo (row-major k)
// wh/wl: [n][k] bf16 hi/lo (transposed)
// 3-product split: hi*hi + hi*lo + lo*hi  (lo*lo dropped, ~2^-16 rel)
// mode 0: out[R*512+C]; mode 1: qh/vh head layout; mode 2: kT layout
// ---------------------------------------------------------------------------
__device__ __forceinline__ void mfma_gemm(
    const unsigned short* __restrict__ xh, const unsigned short* __restrict__ xl,
    const unsigned short* __restrict__ wh, const unsigned short* __restrict__ wl,
    const float* __restrict__ bias, float bscale,
    float* __restrict__ out, int mode)
{
  const int tid = threadIdx.x;
  const int lane = tid & 63, w = tid >> 6;
  const int bm = blockIdx.x * 64 + (w >> 1) * 32;   // this wave's 32x32 tile
  const int bn = blockIdx.y * 64 + (w & 1) * 32;
  const int rA = bm + (lane & 15);
  const int cB = bn + (lane & 15);
  const int kb = (lane >> 4) << 3;                  // k sub-offset 0/8/16/24
  f32x4 acc[2][2] = {};

  for (int k0 = 0; k0 < DMODEL; k0 += 32) {
    const int ko = k0 + kb;
    short8 a0h = *(const short8*)(xh + (size_t)rA * DMODEL + ko);
    short8 a0l = *(const short8*)(xl + (size_t)rA * DMODEL + ko);
    short8 a1h = *(const short8*)(xh + (size_t)(rA + 16) * DMODEL + ko);
    short8 a1l = *(const short8*)(xl + (size_t)(rA + 16) * DMODEL + ko);
    short8 b0h = *(const short8*)(wh + (size_t)cB * DMODEL + ko);
    short8 b0l = *(const short8*)(wl + (size_t)cB * DMODEL + ko);
    short8 b1h = *(const short8*)(wh + (size_t)(cB + 16) * DMODEL + ko);
    short8 b1l = *(const short8*)(wl + (size_t)(cB + 16) * DMODEL + ko);
#define MFMA_(A, B, C) C = __builtin_amdgcn_mfma_f32_16x16x32_bf16(A, B, C, 0, 0, 0)
    MFMA_(a0h, b0h, acc[0][0]); MFMA_(a0h, b0l, acc[0][0]); MFMA_(a0l, b0h, acc[0][0]);
    MFMA_(a0h, b1h, acc[0][1]); MFMA_(a0h, b1l, acc[0][1]); MFMA_(a0l, b1h, acc[0][1]);
    MFMA_(a1h, b0h, acc[1][0]); MFMA_(a1h, b0l, acc[1][0]); MFMA_(a1l, b0h, acc[1][0]);
    MFMA_(a1h, b1h, acc[1][1]); MFMA_(a1h, b1l, acc[1][1]); MFMA_(a1l, b1h, acc[1][1]);
#undef MFMA_
  }

#pragma unroll
  for (int mi = 0; mi < 2; ++mi)
#pragma unroll
    for (int ni = 0; ni < 2; ++ni) {
      const int C = bn + ni * 16 + (lane & 15);
      const float bv = bscale * bias[C];
#pragma unroll
      for (int e = 0; e < 4; ++e) {
        const int R = bm + mi * 16 + ((lane >> 4) << 2) + e;
        const float val = acc[mi][ni][e] + bv;
        if (mode == 0) {
          out[R * DMODEL + C] = val;
        } else {
          const int b = R >> 8, l = R & (LSEQ - 1);
          const int hh = C >> 6, dk = C & 63;
          if (mode == 1) out[((b * NHEAD + hh) * LSEQ + l) * DKH + dk] = val;
          else           out[((b * NHEAD + hh) * DKH + dk) * LSEQ + l] = val;
        }
      }
    }
}

__global__ __launch_bounds__(256) void proj_mfma_kernel(
    const unsigned short* __restrict__ xhi, const unsigned short* __restrict__ xlo,
    const unsigned short* __restrict__ whi, const unsigned short* __restrict__ wlo,
    const float* __restrict__ bq, const float* __restrict__ bk, const float* __restrict__ bv,
    float* __restrict__ qh, float* __restrict__ kT, float* __restrict__ vh)
{
  const int g = blockIdx.z;
  const unsigned short* xh = xhi + (size_t)g * 1024 * DMODEL;
  const unsigned short* xl = xlo + (size_t)g * 1024 * DMODEL;
  const unsigned short* wh = whi + (size_t)g * DMODEL * DMODEL;
  const unsigned short* wl = wlo + (size_t)g * DMODEL * DMODEL;
  if (g == 0)      mfma_gemm(xh, xl, wh, wl, bq, TWO_LOG2E, qh, 1);
  else if (g == 1) mfma_gemm(xh, xl, wh, wl, bk, TWO_LOG2E, kT, 2);
  else             mfma_gemm(xh, xl, wh, wl, bv, 1.0f, vh, 1);
}

__global__ __launch_bounds__(256) void outproj_mfma_kernel(
    const unsigned short* __restrict__ aoh, const unsigned short* __restrict__ aol,
    const unsigned short* __restrict__ whi, const unsigned short* __restrict__ wlo,
    const float* __restrict__ b0, float* __restrict__ out)
{
  mfma_gemm(aoh, aol, whi + (size_t)3 * DMODEL * DMODEL,
            wlo + (size_t)3 * DMODEL * DMODEL, b0, 1.0f, out, 0);
}

// ---------------------------------------------------------------------------
// Fused Bahdanau attention. qh,kT prescaled by 2*log2e.
// t_j = sum_d vp_d * rcp(exp2(q'_d + k'_d) + 1); score = Svp - 2t (const drops in
// softmax): p = exp2(-2log2e*(t - min t)); masked -> t = +1e9.
// Emits attention output directly as bf16 hi/lo for the out-projection.
// ---------------------------------------------------------------------------
__global__ __launch_bounds__(1024) void attn_kernel(
    const float* __restrict__ qh,   // (B,H,L,DK) prescaled
    const float* __restrict__ kT,   // (B,H,DK,L) prescaled
    const float* __restrict__ vh,   // (B,H,L,DK)
    const int* __restrict__ mask,   // (B,L,L)
    const float* __restrict__ vp,   // (H,DK)
    unsigned short* __restrict__ aoh,  // (B*L, D) bf16 hi
    unsigned short* __restrict__ aol)  // (B*L, D) bf16 lo
{
  __shared__ float ksh[DKH][LSEQ];      // 64 KB
  __shared__ float vsh[LSEQ][DKH];      // 64 KB
  __shared__ float qsh[32][DKH];        // 8 KB
  __shared__ float psh[16][LSEQ];       // 16 KB
  __shared__ float vpsh[DKH];

  const int bh = blockIdx.x;            // b*8+h
  const int b = bh >> 3, h = bh & 7;
  const int i0 = blockIdx.y * 32;
  const int tid = threadIdx.x;
  const int lane = tid & 63, w = tid >> 6;   // 16 waves

  const float* kbase = kT + (size_t)bh * DKH * LSEQ;
  for (int t = tid; t < DKH * LSEQ / 4; t += 1024) {
    const int d = t >> 6, j4 = (t & 63) << 2;
    *(float4*)&ksh[d][j4] = *(const float4*)&kbase[d * LSEQ + j4];
  }
  const float* vbase = vh + (size_t)bh * LSEQ * DKH;
  for (int t = tid; t < LSEQ * DKH / 4; t += 1024) {
    const int j = t >> 4, d4 = (t & 15) << 2;
    *(float4*)&vsh[j][d4] = *(const float4*)&vbase[j * DKH + d4];
  }
  if (tid < 512) {
    const float* qbase = qh + ((size_t)bh * LSEQ + i0) * DKH;
    const int r = tid >> 4, d4 = (tid & 15) << 2;
    *(float4*)&qsh[r][d4] = *(const float4*)&qbase[r * DKH + d4];
  }
  if (tid < DKH) vpsh[tid] = vp[h * DKH + tid];
  __syncthreads();

#pragma unroll
  for (int ii = 0; ii < 2; ++ii) {
    const int il = (w << 1) + ii;       // local q-row 0..31
    const int i = i0 + il;

    // ---- t_j accumulation (j = c*64+lane) ----
    float t4[4] = {0.f, 0.f, 0.f, 0.f};
#pragma unroll 4
    for (int g = 0; g < 16; ++g) {
      float q_[4], vpv[4];
      *(float4*)q_ = *(const float4*)&qsh[il][g << 2];
      *(float4*)vpv = *(const float4*)&vpsh[g << 2];
#pragma unroll
      for (int c = 0; c < 4; ++c) {
        const int j = (c << 6) + lane;
#pragma unroll
        for (int t = 0; t < 4; ++t) {
          const float x = q_[t] + ksh[(g << 2) + t][j];
          const float e = __builtin_amdgcn_exp2f(x);
          t4[c] = fmaf(vpv[t], __builtin_amdgcn_rcpf(e + 1.f), t4[c]);
        }
      }
    }

    // ---- mask: masked lanes get t=+1e9 (score -> -inf) ----
    const int* mrow = mask + ((size_t)b * LSEQ + i) * LSEQ;
#pragma unroll
    for (int c = 0; c < 4; ++c) {
      const int mv = mrow[(c << 6) + lane];
      t4[c] = mv ? t4[c] : 1.0e9f;
    }

    // ---- softmax in t-space: p = exp2(-2log2e*(t - min t)) ----
    float m = fminf(fminf(t4[0], t4[1]), fminf(t4[2], t4[3]));
#pragma unroll
    for (int off = 32; off; off >>= 1) m = fminf(m, __shfl_xor(m, off));
    const float m2 = m * TWO_LOG2E;
    float p[4];
    float sum = 0.f;
#pragma unroll
    for (int c = 0; c < 4; ++c) {
      p[c] = __builtin_amdgcn_exp2f(fmaf(t4[c], -TWO_LOG2E, m2));
      sum += p[c];
    }
#pragma unroll
    for (int off = 32; off; off >>= 1) sum += __shfl_xor(sum, off);
    const float rs = __builtin_amdgcn_rcpf(sum);
#pragma unroll
    for (int c = 0; c < 4; ++c) psh[w][(c << 6) + lane] = p[c];

    // ---- PV: cg = j-quarter (lane>>4), qq = dk-quad (lane&15) ----
    const int cg = lane >> 4, qq = lane & 15;
    float o[4] = {0.f, 0.f, 0.f, 0.f};
#pragma unroll 4
    for (int jg = 0; jg < 16; ++jg) {
      float pv[4];
      *(float4*)pv = *(const float4*)&psh[w][(cg << 6) + (jg << 2)];
#pragma unroll
      for (int t = 0; t < 4; ++t) {
        float v_[4];
        *(float4*)v_ = *(const float4*)&vsh[(cg << 6) + (jg << 2) + t][qq << 2];
#pragma unroll
        for (int u = 0; u < 4; ++u) o[u] = fmaf(pv[t], v_[u], o[u]);
      }
    }
#pragma unroll
    for (int off = 16; off <= 32; off <<= 1) {
#pragma unroll
      for (int u = 0; u < 4; ++u) o[u] += __shfl_xor(o[u], off);
    }
    if (lane < 16) {
      float ov[4];
#pragma unroll
      for (int u = 0; u < 4; ++u) ov[u] = o[u] * rs;
      ushort4 h4, l4;
      split4(ov, h4, l4);
      const int base = ((size_t)b * LSEQ + i) * DMODEL + h * DKH + (qq << 2);
      *(ushort4*)&aoh[base] = h4;
      *(ushort4*)&aol[base] = l4;
    }
  }
}

// ---------------------------------------------------------------------------
extern "C" void kernel_launch(void* const* d_in, const int* in_sizes, int n_in,
                              void* d_out, int out_size, void* d_ws, size_t ws_size,
                              hipStream_t stream) {
  const float* q   = (const float*)d_in[0];
  const float* k   = (const float*)d_in[1];
  const float* v   = (const float*)d_in[2];
  const int*  mask = (const int*)d_in[3];
  const float* Wq  = (const float*)d_in[4];
  const float* bq  = (const float*)d_in[5];
  const float* Wk  = (const float*)d_in[6];
  const float* bk  = (const float*)d_in[7];
  const float* Wv  = (const float*)d_in[8];
  const float* bv  = (const float*)d_in[9];
  const float* vp  = (const float*)d_in[10];
  const float* W0  = (const float*)d_in[11];
  const float* b0  = (const float*)d_in[12];
  float* outp = (float*)d_out;

  char* wsb = (char*)d_ws;
  unsigned short* whi = (unsigned short*)(wsb);                    // 2 MB
  unsigned short* wlo = (unsigned short*)(wsb + (2u << 20));       // 2 MB
  unsigned short* xhi = (unsigned short*)(wsb + (4u << 20));       // 3 MB
  unsigned short* xlo = (unsigned short*)(wsb + (7u << 20));       // 3 MB
  float* qh = (float*)(wsb + (10u << 20));                         // 2 MB
  float* kT = (float*)(wsb + (12u << 20));                         // 2 MB
  float* vh = (float*)(wsb + (14u << 20));                         // 2 MB
  unsigned short* aoh = xhi;   // overlay: x(q,k,v) dead after proj
  unsigned short* aol = xlo;

  prep_kernel<<<dim3(32, 16, 7), 256, 0, stream>>>(q, k, v, Wq, Wk, Wv, W0,
                                                   xhi, xlo, whi, wlo);
  proj_mfma_kernel<<<dim3(16, 8, 3), 256, 0, stream>>>(xhi, xlo, whi, wlo,
                                                       bq, bk, bv, qh, kT, vh);
  attn_kernel<<<dim3(32, 8), 1024, 0, stream>>>(qh, kT, vh, mask, vp, aoh, aol);
  outproj_mfma_kernel<<<dim3(16, 8), 256, 0, stream>>>(aoh, aol, whi, wlo, b0, outp);
}

// Round 4
// 141.997 us; speedup vs baseline: 1.3664x; 1.3664x over previous
//
#include <hip/hip_runtime.h>

#define LSEQ 256
#define DMODEL 512
#define NHEAD 8
#define DKH 64
#define BATCH 4

#define TWO_LOG2E 2.885390081777927f

using short8 = __attribute__((ext_vector_type(8))) short;
using f32x4  = __attribute__((ext_vector_type(4))) float;

// split fp32 -> truncated bf16 hi + bf16(lo remainder)
__device__ __forceinline__ void split4(const float* f, ushort4& h, ushort4& l) {
  unsigned short hh[4], ll[4];
#pragma unroll
  for (int j = 0; j < 4; ++j) {
    unsigned int u = __float_as_uint(f[j]);
    hh[j] = (unsigned short)(u >> 16);
    float hf = __uint_as_float(u & 0xFFFF0000u);
    ll[j] = (unsigned short)(__float_as_uint(f[j] - hf) >> 16);
  }
  h = make_ushort4(hh[0], hh[1], hh[2], hh[3]);
  l = make_ushort4(ll[0], ll[1], ll[2], ll[3]);
}

// ---------------------------------------------------------------------------
// prep: z=0..2 -> convert X (q,k,v) to bf16 hi/lo [z][1024][512]
//       z=3..6 -> convert+transpose W (Wq,Wk,Wv,W0) to [g][n][k] hi/lo
//                 (Wq,Wk prescaled by 2*log2e so attn exp2 needs no multiply)
// ---------------------------------------------------------------------------
__global__ __launch_bounds__(256) void prep_kernel(
    const float* __restrict__ q, const float* __restrict__ k, const float* __restrict__ v,
    const float* __restrict__ Wq, const float* __restrict__ Wk,
    const float* __restrict__ Wv, const float* __restrict__ W0,
    unsigned short* __restrict__ xhi, unsigned short* __restrict__ xlo,
    unsigned short* __restrict__ whi, unsigned short* __restrict__ wlo)
{
  const int z = blockIdx.z;
  const int tid = threadIdx.x;
  if (z < 3) {
    const float* X = (z == 0) ? q : (z == 1) ? k : v;
    const int r = blockIdx.x * 32 + (tid >> 3);
    const int c = blockIdx.y * 32 + ((tid & 7) << 2);
    float4 f = *(const float4*)&X[r * DMODEL + c];
    ushort4 h4, l4;
    split4((const float*)&f, h4, l4);
    const int base = (z * 1024 + r) * DMODEL + c;
    *(ushort4*)&xhi[base] = h4;
    *(ushort4*)&xlo[base] = l4;
  } else {
    if (blockIdx.x >= 16) return;
    const int g = z - 3;
    const float* W = (g == 0) ? Wq : (g == 1) ? Wk : (g == 2) ? Wv : W0;
    const float scale = (g < 2) ? TWO_LOG2E : 1.0f;
    const int k0 = blockIdx.x * 32, n0 = blockIdx.y * 32;
    __shared__ float tile[32][36];
    {
      const int r = tid >> 3, c = (tid & 7) << 2;
      float4 f = *(const float4*)&W[(k0 + r) * DMODEL + n0 + c];
      tile[r][c + 0] = f.x * scale;
      tile[r][c + 1] = f.y * scale;
      tile[r][c + 2] = f.z * scale;
      tile[r][c + 3] = f.w * scale;
    }
    __syncthreads();
    const int n = tid >> 3, kk = (tid & 7) << 2;
    float x[4];
#pragma unroll
    for (int j = 0; j < 4; ++j) x[j] = tile[kk + j][n];
    ushort4 h4, l4;
    split4(x, h4, l4);
    const int base = (g * DMODEL + n0 + n) * DMODEL + k0 + kk;
    *(ushort4*)&whi[base] = h4;
    *(ushort4*)&wlo[base] = l4;
  }
}

// ---------------------------------------------------------------------------
// LDS-staged bf16-split MFMA GEMM. Block tile 64x64, BK=64, 4 waves (each a
// 32x32 quadrant, 2x2 frags of 16x16x32). LDS tiles [64 rows][8 chunks of
// 8 bf16], chunk XOR-swizzled with (row&7) so frag ds_read_b128 is
// conflict-free; staging pre-applies the same XOR on the GLOBAL source
// (both-sides involution). Reg-staged: issue loads for step t+1 early,
// compute, barrier, ds_write, barrier (T14 overlap).
// 3-product split: hi*hi + hi*lo + lo*hi.
// mode 0: out[R*512+C]; mode 1: qh/vh head layout; mode 2: kT layout
// ---------------------------------------------------------------------------
__device__ __forceinline__ void mfma_gemm(
    const unsigned short* __restrict__ xh, const unsigned short* __restrict__ xl,
    const unsigned short* __restrict__ wh, const unsigned short* __restrict__ wl,
    const float* __restrict__ bias, float bscale,
    float* __restrict__ out, int mode)
{
  __shared__ short8 ldsT[4][512];   // [Ah,Al,Bh,Bl][64 rows * 8 chunks] = 32 KB
  const int tid = threadIdx.x;
  const int lane = tid & 63, w = tid >> 6;
  const int bm0 = blockIdx.x * 64, bn0 = blockIdx.y * 64;

  // staging: thread owns slots tid and tid+256 of each tile.
  // slot s: row=s>>3, c=s&7; holds global chunk (c ^ (row&7)).
  const int r0 = tid >> 3, c0 = tid & 7;
  const int g0 = c0 ^ (r0 & 7);
  const int r1 = r0 + 32;
  const int g1 = c0 ^ (r1 & 7);
  const size_t offA0 = (size_t)(bm0 + r0) * DMODEL + g0 * 8;
  const size_t offA1 = (size_t)(bm0 + r1) * DMODEL + g1 * 8;
  const size_t offB0 = (size_t)(bn0 + r0) * DMODEL + g0 * 8;
  const size_t offB1 = (size_t)(bn0 + r1) * DMODEL + g1 * 8;

  const int mrb = (w >> 1) << 5, ncb = (w & 1) << 5;
  const int l15 = lane & 15, lh = lane >> 4, l7 = lane & 7;

  short8 st[8];
#define LOADS(K)                                        \
  { st[0] = *(const short8*)(xh + offA0 + (K));         \
    st[1] = *(const short8*)(xh + offA1 + (K));         \
    st[2] = *(const short8*)(xl + offA0 + (K));         \
    st[3] = *(const short8*)(xl + offA1 + (K));         \
    st[4] = *(const short8*)(wh + offB0 + (K));         \
    st[5] = *(const short8*)(wh + offB1 + (K));         \
    st[6] = *(const short8*)(wl + offB0 + (K));         \
    st[7] = *(const short8*)(wl + offB1 + (K)); }
#define WRITES                                          \
  { ldsT[0][tid] = st[0]; ldsT[0][tid + 256] = st[1];   \
    ldsT[1][tid] = st[2]; ldsT[1][tid + 256] = st[3];   \
    ldsT[2][tid] = st[4]; ldsT[2][tid + 256] = st[5];   \
    ldsT[3][tid] = st[6]; ldsT[3][tid + 256] = st[7]; }

  f32x4 acc[2][2] = {};
  LOADS(0);
  WRITES;
  __syncthreads();

  for (int t = 0; t < 8; ++t) {
    if (t < 7) LOADS((t + 1) * 64);
#pragma unroll
    for (int s = 0; s < 2; ++s) {
      const int chb = (s << 2) + lh;
      const int ra0 = (mrb + l15) * 8 + (chb ^ l7);
      const int ra1 = (mrb + 16 + l15) * 8 + (chb ^ l7);
      const int rb0 = (ncb + l15) * 8 + (chb ^ l7);
      const int rb1 = (ncb + 16 + l15) * 8 + (chb ^ l7);
      short8 a0h = ldsT[0][ra0], a0l = ldsT[1][ra0];
      short8 a1h = ldsT[0][ra1], a1l = ldsT[1][ra1];
      short8 b0h = ldsT[2][rb0], b0l = ldsT[3][rb0];
      short8 b1h = ldsT[2][rb1], b1l = ldsT[3][rb1];
#define MFMA_(A, B, C) C = __builtin_amdgcn_mfma_f32_16x16x32_bf16(A, B, C, 0, 0, 0)
      MFMA_(a0h, b0h, acc[0][0]); MFMA_(a0h, b0l, acc[0][0]); MFMA_(a0l, b0h, acc[0][0]);
      MFMA_(a0h, b1h, acc[0][1]); MFMA_(a0h, b1l, acc[0][1]); MFMA_(a0l, b1h, acc[0][1]);
      MFMA_(a1h, b0h, acc[1][0]); MFMA_(a1h, b0l, acc[1][0]); MFMA_(a1l, b0h, acc[1][0]);
      MFMA_(a1h, b1h, acc[1][1]); MFMA_(a1h, b1l, acc[1][1]); MFMA_(a1l, b1h, acc[1][1]);
#undef MFMA_
    }
    __syncthreads();
    if (t < 7) { WRITES; __syncthreads(); }
  }
#undef LOADS
#undef WRITES

  const int bm = bm0 + mrb, bn = bn0 + ncb;
#pragma unroll
  for (int mi = 0; mi < 2; ++mi)
#pragma unroll
    for (int ni = 0; ni < 2; ++ni) {
      const int C = bn + ni * 16 + l15;
      const float bv = bscale * bias[C];
#pragma unroll
      for (int e = 0; e < 4; ++e) {
        const int R = bm + mi * 16 + (lh << 2) + e;
        const float val = acc[mi][ni][e] + bv;
        if (mode == 0) {
          out[R * DMODEL + C] = val;
        } else {
          const int b = R >> 8, l = R & (LSEQ - 1);
          const int hh = C >> 6, dk = C & 63;
          if (mode == 1) out[((b * NHEAD + hh) * LSEQ + l) * DKH + dk] = val;
          else           out[((b * NHEAD + hh) * DKH + dk) * LSEQ + l] = val;
        }
      }
    }
}

__global__ __launch_bounds__(256) void proj_mfma_kernel(
    const unsigned short* __restrict__ xhi, const unsigned short* __restrict__ xlo,
    const unsigned short* __restrict__ whi, const unsigned short* __restrict__ wlo,
    const float* __restrict__ bq, const float* __restrict__ bk, const float* __restrict__ bv,
    float* __restrict__ qh, float* __restrict__ kT, float* __restrict__ vh)
{
  const int g = blockIdx.z;
  const unsigned short* xh = xhi + (size_t)g * 1024 * DMODEL;
  const unsigned short* xl = xlo + (size_t)g * 1024 * DMODEL;
  const unsigned short* wh = whi + (size_t)g * DMODEL * DMODEL;
  const unsigned short* wl = wlo + (size_t)g * DMODEL * DMODEL;
  if (g == 0)      mfma_gemm(xh, xl, wh, wl, bq, TWO_LOG2E, qh, 1);
  else if (g == 1) mfma_gemm(xh, xl, wh, wl, bk, TWO_LOG2E, kT, 2);
  else             mfma_gemm(xh, xl, wh, wl, bv, 1.0f, vh, 1);
}

__global__ __launch_bounds__(256) void outproj_mfma_kernel(
    const unsigned short* __restrict__ aoh, const unsigned short* __restrict__ aol,
    const unsigned short* __restrict__ whi, const unsigned short* __restrict__ wlo,
    const float* __restrict__ b0, float* __restrict__ out)
{
  mfma_gemm(aoh, aol, whi + (size_t)3 * DMODEL * DMODEL,
            wlo + (size_t)3 * DMODEL * DMODEL, b0, 1.0f, out, 0);
}

// ---------------------------------------------------------------------------
// Fused Bahdanau attention. qh,kT prescaled by 2*log2e.
// t_j = sum_d vp_d * rcp(exp2(q'_d + k'_d) + 1); softmax in t-space:
// p = exp2(-2log2e*(t - min t)); masked -> t = +1e9.
// 512 threads / 8 waves; each wave computes 4 q-rows JOINTLY in the score
// phase (each ksh value loaded once, reused 4x; 16 independent trans chains).
// Emits attention output as bf16 hi/lo for the out-projection.
// ---------------------------------------------------------------------------
__global__ __launch_bounds__(512) void attn_kernel(
    const float* __restrict__ qh,   // (B,H,L,DK) prescaled
    const float* __restrict__ kT,   // (B,H,DK,L) prescaled
    const float* __restrict__ vh,   // (B,H,L,DK)
    const int* __restrict__ mask,   // (B,L,L)
    const float* __restrict__ vp,   // (H,DK)
    unsigned short* __restrict__ aoh,  // (B*L, D) bf16 hi
    unsigned short* __restrict__ aol)  // (B*L, D) bf16 lo
{
  __shared__ float ksh[DKH][LSEQ];      // 64 KB
  __shared__ float vsh[LSEQ][DKH];      // 64 KB
  __shared__ float qsh[32][DKH];        // 8 KB
  __shared__ float psh[8][LSEQ];        // 8 KB (one row per wave at a time)
  __shared__ float vpsh[DKH];

  const int bh = blockIdx.x;            // b*8+h
  const int b = bh >> 3, h = bh & 7;
  const int i0 = blockIdx.y * 32;
  const int tid = threadIdx.x;
  const int lane = tid & 63, w = tid >> 6;   // 8 waves

  const float* kbase = kT + (size_t)bh * DKH * LSEQ;
  for (int t = tid; t < DKH * LSEQ / 4; t += 512) {
    const int d = t >> 6, j4 = (t & 63) << 2;
    *(float4*)&ksh[d][j4] = *(const float4*)&kbase[d * LSEQ + j4];
  }
  const float* vbase = vh + (size_t)bh * LSEQ * DKH;
  for (int t = tid; t < LSEQ * DKH / 4; t += 512) {
    const int j = t >> 4, d4 = (t & 15) << 2;
    *(float4*)&vsh[j][d4] = *(const float4*)&vbase[j * DKH + d4];
  }
  {
    const float* qbase = qh + ((size_t)bh * LSEQ + i0) * DKH;
    const int r = tid >> 4, d4 = (tid & 15) << 2;
    *(float4*)&qsh[r][d4] = *(const float4*)&qbase[r * DKH + d4];
  }
  if (tid < DKH) vpsh[tid] = vp[h * DKH + tid];
  __syncthreads();

  // ---- score phase: 4 rows jointly. tj[r][c] for rows w*4+r, cols c*64+lane
  float tj[4][4] = {};
#pragma unroll 2
  for (int g = 0; g < 16; ++g) {
    float kv[16];     // [t][c]
#pragma unroll
    for (int t = 0; t < 4; ++t)
#pragma unroll
      for (int c = 0; c < 4; ++c)
        kv[t * 4 + c] = ksh[(g << 2) + t][(c << 6) + lane];
    float vpv[4];
    *(float4*)vpv = *(const float4*)&vpsh[g << 2];
#pragma unroll
    for (int r = 0; r < 4; ++r) {
      float q_[4];
      *(float4*)q_ = *(const float4*)&qsh[(w << 2) + r][g << 2];
#pragma unroll
      for (int t = 0; t < 4; ++t)
#pragma unroll
        for (int c = 0; c < 4; ++c) {
          const float x = q_[t] + kv[t * 4 + c];
          const float e = __builtin_amdgcn_exp2f(x);
          tj[r][c] = fmaf(vpv[t], __builtin_amdgcn_rcpf(e + 1.f), tj[r][c]);
        }
    }
  }

  // ---- per-row: mask, softmax (t-space), PV ----
  const int cg = lane >> 4, qq = lane & 15;
#pragma unroll
  for (int r = 0; r < 4; ++r) {
    const int i = i0 + (w << 2) + r;
    const int* mrow = mask + ((size_t)b * LSEQ + i) * LSEQ;
    float t4[4];
#pragma unroll
    for (int c = 0; c < 4; ++c) {
      const int mv = mrow[(c << 6) + lane];
      t4[c] = mv ? tj[r][c] : 1.0e9f;
    }
    float m = fminf(fminf(t4[0], t4[1]), fminf(t4[2], t4[3]));
#pragma unroll
    for (int off = 32; off; off >>= 1) m = fminf(m, __shfl_xor(m, off));
    const float m2 = m * TWO_LOG2E;
    float p[4];
    float sum = 0.f;
#pragma unroll
    for (int c = 0; c < 4; ++c) {
      p[c] = __builtin_amdgcn_exp2f(fmaf(t4[c], -TWO_LOG2E, m2));
      sum += p[c];
    }
#pragma unroll
    for (int off = 32; off; off >>= 1) sum += __shfl_xor(sum, off);
    const float rs = __builtin_amdgcn_rcpf(sum);
#pragma unroll
    for (int c = 0; c < 4; ++c) psh[w][(c << 6) + lane] = p[c];

    float o[4] = {0.f, 0.f, 0.f, 0.f};
#pragma unroll 4
    for (int jg = 0; jg < 16; ++jg) {
      float pv[4];
      *(float4*)pv = *(const float4*)&psh[w][(cg << 6) + (jg << 2)];
#pragma unroll
      for (int t = 0; t < 4; ++t) {
        float v_[4];
        *(float4*)v_ = *(const float4*)&vsh[(cg << 6) + (jg << 2) + t][qq << 2];
#pragma unroll
        for (int u = 0; u < 4; ++u) o[u] = fmaf(pv[t], v_[u], o[u]);
      }
    }
#pragma unroll
    for (int off = 16; off <= 32; off <<= 1) {
#pragma unroll
      for (int u = 0; u < 4; ++u) o[u] += __shfl_xor(o[u], off);
    }
    if (lane < 16) {
      float ov[4];
#pragma unroll
      for (int u = 0; u < 4; ++u) ov[u] = o[u] * rs;
      ushort4 h4, l4;
      split4(ov, h4, l4);
      const int base = ((size_t)b * LSEQ + i) * DMODEL + h * DKH + (qq << 2);
      *(ushort4*)&aoh[base] = h4;
      *(ushort4*)&aol[base] = l4;
    }
  }
}

// ---------------------------------------------------------------------------
extern "C" void kernel_launch(void* const* d_in, const int* in_sizes, int n_in,
                              void* d_out, int out_size, void* d_ws, size_t ws_size,
                              hipStream_t stream) {
  const float* q   = (const float*)d_in[0];
  const float* k   = (const float*)d_in[1];
  const float* v   = (const float*)d_in[2];
  const int*  mask = (const int*)d_in[3];
  const float* Wq  = (const float*)d_in[4];
  const float* bq  = (const float*)d_in[5];
  const float* Wk  = (const float*)d_in[6];
  const float* bk  = (const float*)d_in[7];
  const float* Wv  = (const float*)d_in[8];
  const float* bv  = (const float*)d_in[9];
  const float* vp  = (const float*)d_in[10];
  const float* W0  = (const float*)d_in[11];
  const float* b0  = (const float*)d_in[12];
  float* outp = (float*)d_out;

  char* wsb = (char*)d_ws;
  unsigned short* whi = (unsigned short*)(wsb);                    // 2 MB
  unsigned short* wlo = (unsigned short*)(wsb + (2u << 20));       // 2 MB
  unsigned short* xhi = (unsigned short*)(wsb + (4u << 20));       // 3 MB
  unsigned short* xlo = (unsigned short*)(wsb + (7u << 20));       // 3 MB
  float* qh = (float*)(wsb + (10u << 20));                         // 2 MB
  float* kT = (float*)(wsb + (12u << 20));                         // 2 MB
  float* vh = (float*)(wsb + (14u << 20));                         // 2 MB
  unsigned short* aoh = xhi;   // overlay: x(q,k,v) dead after proj
  unsigned short* aol = xlo;

  prep_kernel<<<dim3(32, 16, 7), 256, 0, stream>>>(q, k, v, Wq, Wk, Wv, W0,
                                                   xhi, xlo, whi, wlo);
  proj_mfma_kernel<<<dim3(16, 8, 3), 256, 0, stream>>>(xhi, xlo, whi, wlo,
                                                       bq, bk, bv, qh, kT, vh);
  attn_kernel<<<dim3(32, 8), 512, 0, stream>>>(qh, kT, vh, mask, vp, aoh, aol);
  outproj_mfma_kernel<<<dim3(16, 8), 256, 0, stream>>>(aoh, aol, whi, wlo, b0, outp);
}

// Round 5
// 139.702 us; speedup vs baseline: 1.3888x; 1.0164x over previous
//
#include <hip/hip_runtime.h>

#define LSEQ 256
#define DMODEL 512
#define NHEAD 8
#define DKH 64
#define BATCH 4

#define TWO_LOG2E 2.885390081777927f

using short8 = __attribute__((ext_vector_type(8))) short;
using f32x4  = __attribute__((ext_vector_type(4))) float;

// split fp32 -> truncated bf16 hi + bf16(lo remainder)
__device__ __forceinline__ void split4(const float* f, ushort4& h, ushort4& l) {
  unsigned short hh[4], ll[4];
#pragma unroll
  for (int j = 0; j < 4; ++j) {
    unsigned int u = __float_as_uint(f[j]);
    hh[j] = (unsigned short)(u >> 16);
    float hf = __uint_as_float(u & 0xFFFF0000u);
    ll[j] = (unsigned short)(__float_as_uint(f[j] - hf) >> 16);
  }
  h = make_ushort4(hh[0], hh[1], hh[2], hh[3]);
  l = make_ushort4(ll[0], ll[1], ll[2], ll[3]);
}

__device__ __forceinline__ void split8(float4 f0, float4 f1, short8& h, short8& l) {
  float f[8] = {f0.x, f0.y, f0.z, f0.w, f1.x, f1.y, f1.z, f1.w};
#pragma unroll
  for (int j = 0; j < 8; ++j) {
    unsigned int u = __float_as_uint(f[j]);
    h[j] = (short)(u >> 16);
    float hf = __uint_as_float(u & 0xFFFF0000u);
    l[j] = (short)(__float_as_uint(f[j] - hf) >> 16);
  }
}

// ---------------------------------------------------------------------------
// prep_w: convert+transpose W (Wq,Wk,Wv,W0) to [g][n][k] bf16 hi/lo.
// Wq,Wk prescaled by 2*log2e so attn's exp2 needs no multiply.
// grid (16,16,4): k0=bx*32, n0=by*32, g=z.
// ---------------------------------------------------------------------------
__global__ __launch_bounds__(256) void prep_w_kernel(
    const float* __restrict__ Wq, const float* __restrict__ Wk,
    const float* __restrict__ Wv, const float* __restrict__ W0,
    unsigned short* __restrict__ whi, unsigned short* __restrict__ wlo)
{
  const int tid = threadIdx.x;
  const int g = blockIdx.z;
  const float* W = (g == 0) ? Wq : (g == 1) ? Wk : (g == 2) ? Wv : W0;
  const float scale = (g < 2) ? TWO_LOG2E : 1.0f;
  const int k0 = blockIdx.x * 32, n0 = blockIdx.y * 32;
  __shared__ float tile[32][36];
  {
    const int r = tid >> 3, c = (tid & 7) << 2;
    float4 f = *(const float4*)&W[(k0 + r) * DMODEL + n0 + c];
    tile[r][c + 0] = f.x * scale;
    tile[r][c + 1] = f.y * scale;
    tile[r][c + 2] = f.z * scale;
    tile[r][c + 3] = f.w * scale;
  }
  __syncthreads();
  const int n = tid >> 3, kk = (tid & 7) << 2;
  float x[4];
#pragma unroll
  for (int j = 0; j < 4; ++j) x[j] = tile[kk + j][n];
  ushort4 h4, l4;
  split4(x, h4, l4);
  const int base = (g * DMODEL + n0 + n) * DMODEL + k0 + kk;
  *(ushort4*)&whi[base] = h4;
  *(ushort4*)&wlo[base] = l4;
}

// ---------------------------------------------------------------------------
// Double-buffered bf16-split MFMA GEMM, fp32 A source (converted in-kernel
// during staging). Block tile 64x64, BK=64, 4 waves (each 32x32 quadrant).
// LDS [buf][Ah,Al,Bh,Bl][row*8+chunk], chunk XOR-swizzled with (row&7);
// staging pre-applies the same XOR on the global source. One barrier/step.
// 3-product split: hi*hi + hi*lo + lo*hi.
// mode 0: out[R*512+C]; mode 1: qh/vh head layout; mode 2: kT layout
// ---------------------------------------------------------------------------
__device__ __forceinline__ void gemm_fp32A(
    const float* __restrict__ X,
    const unsigned short* __restrict__ wh, const unsigned short* __restrict__ wl,
    const float* __restrict__ bias, float bscale,
    float* __restrict__ out, int mode, int bx, int by)
{
  __shared__ short8 lds[2][4][512];   // 64 KB
  const int tid = threadIdx.x;
  const int lane = tid & 63, w = tid >> 6;
  const int bm0 = bx * 64, bn0 = by * 64;

  const int r0 = tid >> 3, c0 = tid & 7, g0 = c0 ^ (r0 & 7);
  const int r1 = r0 + 32,  g1 = c0 ^ (r1 & 7);
  const size_t aoff0 = (size_t)(bm0 + r0) * DMODEL + g0 * 8;
  const size_t aoff1 = (size_t)(bm0 + r1) * DMODEL + g1 * 8;
  const size_t boff0 = (size_t)(bn0 + r0) * DMODEL + g0 * 8;
  const size_t boff1 = (size_t)(bn0 + r1) * DMODEL + g1 * 8;

  const int mrb = (w >> 1) << 5, ncb = (w & 1) << 5;
  const int l15 = lane & 15, lh = lane >> 4, l7 = lane & 7;

  float4 af00, af01, af10, af11;
  short8 b0h, b0l, b1h, b1l;

#define LOADS(K)                                                  \
  { af00 = *(const float4*)(X + aoff0 + (K));                     \
    af01 = *(const float4*)(X + aoff0 + (K) + 4);                 \
    af10 = *(const float4*)(X + aoff1 + (K));                     \
    af11 = *(const float4*)(X + aoff1 + (K) + 4);                 \
    b0h = *(const short8*)(wh + boff0 + (K));                     \
    b0l = *(const short8*)(wl + boff0 + (K));                     \
    b1h = *(const short8*)(wh + boff1 + (K));                     \
    b1l = *(const short8*)(wl + boff1 + (K)); }
#define WRITES(BUF)                                               \
  { short8 h_, l_;                                                \
    split8(af00, af01, h_, l_);                                   \
    lds[BUF][0][tid] = h_; lds[BUF][1][tid] = l_;                 \
    split8(af10, af11, h_, l_);                                   \
    lds[BUF][0][tid + 256] = h_; lds[BUF][1][tid + 256] = l_;     \
    lds[BUF][2][tid] = b0h; lds[BUF][3][tid] = b0l;               \
    lds[BUF][2][tid + 256] = b1h; lds[BUF][3][tid + 256] = b1l; }

  f32x4 acc[2][2] = {};
  LOADS(0);
  WRITES(0);
  __syncthreads();

  int cur = 0;
  for (int t = 0; t < 8; ++t) {
    if (t < 7) LOADS((t + 1) * 64);
#pragma unroll
    for (int s = 0; s < 2; ++s) {
      const int chb = (s << 2) + lh;
      const int ra0 = (mrb + l15) * 8 + (chb ^ l7);
      const int ra1 = (mrb + 16 + l15) * 8 + (chb ^ l7);
      const int rb0 = (ncb + l15) * 8 + (chb ^ l7);
      const int rb1 = (ncb + 16 + l15) * 8 + (chb ^ l7);
      short8 a0h = lds[cur][0][ra0], a0l = lds[cur][1][ra0];
      short8 a1h = lds[cur][0][ra1], a1l = lds[cur][1][ra1];
      short8 w0h = lds[cur][2][rb0], w0l = lds[cur][3][rb0];
      short8 w1h = lds[cur][2][rb1], w1l = lds[cur][3][rb1];
#define MFMA_(A, B, C) C = __builtin_amdgcn_mfma_f32_16x16x32_bf16(A, B, C, 0, 0, 0)
      MFMA_(a0h, w0h, acc[0][0]); MFMA_(a0h, w0l, acc[0][0]); MFMA_(a0l, w0h, acc[0][0]);
      MFMA_(a0h, w1h, acc[0][1]); MFMA_(a0h, w1l, acc[0][1]); MFMA_(a0l, w1h, acc[0][1]);
      MFMA_(a1h, w0h, acc[1][0]); MFMA_(a1h, w0l, acc[1][0]); MFMA_(a1l, w0h, acc[1][0]);
      MFMA_(a1h, w1h, acc[1][1]); MFMA_(a1h, w1l, acc[1][1]); MFMA_(a1l, w1h, acc[1][1]);
#undef MFMA_
    }
    if (t < 7) WRITES(cur ^ 1);
    __syncthreads();
    cur ^= 1;
  }
#undef LOADS
#undef WRITES

  const int bm = bm0 + mrb, bn = bn0 + ncb;
#pragma unroll
  for (int mi = 0; mi < 2; ++mi)
#pragma unroll
    for (int ni = 0; ni < 2; ++ni) {
      const int C = bn + ni * 16 + l15;
      const float bv = bscale * bias[C];
#pragma unroll
      for (int e = 0; e < 4; ++e) {
        const int R = bm + mi * 16 + (lh << 2) + e;
        const float val = acc[mi][ni][e] + bv;
        if (mode == 0) {
          out[R * DMODEL + C] = val;
        } else {
          const int b = R >> 8, l = R & (LSEQ - 1);
          const int hh = C >> 6, dk = C & 63;
          if (mode == 1) out[((b * NHEAD + hh) * LSEQ + l) * DKH + dk] = val;
          else           out[((b * NHEAD + hh) * DKH + dk) * LSEQ + l] = val;
        }
      }
    }
}

__global__ __launch_bounds__(256) void proj_mfma_kernel(
    const float* __restrict__ q, const float* __restrict__ k, const float* __restrict__ v,
    const unsigned short* __restrict__ whi, const unsigned short* __restrict__ wlo,
    const float* __restrict__ bq, const float* __restrict__ bk, const float* __restrict__ bv,
    float* __restrict__ qh, float* __restrict__ kT, float* __restrict__ vh)
{
  // XCD-bijective swizzle over 384 blocks (=48*8)
  int lin = blockIdx.x + 16 * blockIdx.y + 128 * blockIdx.z;
  lin = (lin & 7) * 48 + (lin >> 3);
  const int bx = lin & 15, by = (lin >> 4) & 7, g = lin >> 7;
  const unsigned short* wh = whi + (size_t)g * DMODEL * DMODEL;
  const unsigned short* wl = wlo + (size_t)g * DMODEL * DMODEL;
  if (g == 0)      gemm_fp32A(q, wh, wl, bq, TWO_LOG2E, qh, 1, bx, by);
  else if (g == 1) gemm_fp32A(k, wh, wl, bk, TWO_LOG2E, kT, 2, bx, by);
  else             gemm_fp32A(v, wh, wl, bv, 1.0f, vh, 1, bx, by);
}

__global__ __launch_bounds__(256) void outproj_mfma_kernel(
    const float* __restrict__ ao,
    const unsigned short* __restrict__ whi, const unsigned short* __restrict__ wlo,
    const float* __restrict__ b0, float* __restrict__ out)
{
  int lin = blockIdx.x + 16 * blockIdx.y;     // 128 blocks = 16*8
  lin = (lin & 7) * 16 + (lin >> 3);
  const int bx = lin & 15, by = lin >> 4;
  gemm_fp32A(ao, whi + (size_t)3 * DMODEL * DMODEL,
             wlo + (size_t)3 * DMODEL * DMODEL, b0, 1.0f, out, 0, bx, by);
}

// ---------------------------------------------------------------------------
// Fused Bahdanau attention. qh,kT prescaled by 2*log2e.
// t_j = sum_d vp_d * rcp(exp2(q'_d + k'_d) + 1); softmax in t-space:
// p = exp2(-2log2e*(t - min t)); masked -> t = +1e9.
// 1024 threads / 16 waves, 2 q-rows per wave (kv regs reused across rows).
// 152 KB LDS, 1 block/CU -> 4 waves/SIMD. Output ao fp32.
// ---------------------------------------------------------------------------
__global__ __launch_bounds__(1024, 4) void attn_kernel(
    const float* __restrict__ qh,   // (B,H,L,DK) prescaled
    const float* __restrict__ kT,   // (B,H,DK,L) prescaled
    const float* __restrict__ vh,   // (B,H,L,DK)
    const int* __restrict__ mask,   // (B,L,L)
    const float* __restrict__ vp,   // (H,DK)
    float* __restrict__ ao)         // (B*L, D) fp32
{
  __shared__ float ksh[DKH][LSEQ];      // 64 KB
  __shared__ float vsh[LSEQ][DKH];      // 64 KB
  __shared__ float qsh[32][DKH];        // 8 KB
  __shared__ float psh[16][LSEQ];       // 16 KB (one row per wave at a time)
  __shared__ float vpsh[DKH];

  const int bh = blockIdx.x;            // b*8+h
  const int b = bh >> 3, h = bh & 7;
  const int i0 = blockIdx.y * 32;
  const int tid = threadIdx.x;
  const int lane = tid & 63, w = tid >> 6;   // 16 waves

  const float* kbase = kT + (size_t)bh * DKH * LSEQ;
  for (int t = tid; t < DKH * LSEQ / 4; t += 1024) {
    const int d = t >> 6, j4 = (t & 63) << 2;
    *(float4*)&ksh[d][j4] = *(const float4*)&kbase[d * LSEQ + j4];
  }
  const float* vbase = vh + (size_t)bh * LSEQ * DKH;
  for (int t = tid; t < LSEQ * DKH / 4; t += 1024) {
    const int j = t >> 4, d4 = (t & 15) << 2;
    *(float4*)&vsh[j][d4] = *(const float4*)&vbase[j * DKH + d4];
  }
  if (tid < 512) {
    const float* qbase = qh + ((size_t)bh * LSEQ + i0) * DKH;
    const int r = tid >> 4, d4 = (tid & 15) << 2;
    *(float4*)&qsh[r][d4] = *(const float4*)&qbase[r * DKH + d4];
  }
  if (tid < DKH) vpsh[tid] = vp[h * DKH + tid];
  __syncthreads();

  // ---- score phase: 2 rows per wave. tj[r][c]: rows w*2+r, cols c*64+lane
  float tj[2][4] = {};
#pragma unroll 2
  for (int g = 0; g < 16; ++g) {
    float kv[16];     // [t][c]
#pragma unroll
    for (int t = 0; t < 4; ++t)
#pragma unroll
      for (int c = 0; c < 4; ++c)
        kv[t * 4 + c] = ksh[(g << 2) + t][(c << 6) + lane];
    float vpv[4];
    *(float4*)vpv = *(const float4*)&vpsh[g << 2];
#pragma unroll
    for (int r = 0; r < 2; ++r) {
      float q_[4];
      *(float4*)q_ = *(const float4*)&qsh[(w << 1) + r][g << 2];
#pragma unroll
      for (int t = 0; t < 4; ++t)
#pragma unroll
        for (int c = 0; c < 4; ++c) {
          const float x = q_[t] + kv[t * 4 + c];
          const float e = __builtin_amdgcn_exp2f(x);
          tj[r][c] = fmaf(vpv[t], __builtin_amdgcn_rcpf(e + 1.f), tj[r][c]);
        }
    }
  }

  // ---- per-row: mask, softmax (t-space), PV ----
  const int cg = lane >> 4, qq = lane & 15;
#pragma unroll
  for (int r = 0; r < 2; ++r) {
    const int i = i0 + (w << 1) + r;
    const int* mrow = mask + ((size_t)b * LSEQ + i) * LSEQ;
    float t4[4];
#pragma unroll
    for (int c = 0; c < 4; ++c) {
      const int mv = mrow[(c << 6) + lane];
      t4[c] = mv ? tj[r][c] : 1.0e9f;
    }
    float m = fminf(fminf(t4[0], t4[1]), fminf(t4[2], t4[3]));
#pragma unroll
    for (int off = 32; off; off >>= 1) m = fminf(m, __shfl_xor(m, off));
    const float m2 = m * TWO_LOG2E;
    float p[4];
    float sum = 0.f;
#pragma unroll
    for (int c = 0; c < 4; ++c) {
      p[c] = __builtin_amdgcn_exp2f(fmaf(t4[c], -TWO_LOG2E, m2));
      sum += p[c];
    }
#pragma unroll
    for (int off = 32; off; off >>= 1) sum += __shfl_xor(sum, off);
    const float rs = __builtin_amdgcn_rcpf(sum);
#pragma unroll
    for (int c = 0; c < 4; ++c) psh[w][(c << 6) + lane] = p[c];

    float o[4] = {0.f, 0.f, 0.f, 0.f};
#pragma unroll 4
    for (int jg = 0; jg < 16; ++jg) {
      float pv[4];
      *(float4*)pv = *(const float4*)&psh[w][(cg << 6) + (jg << 2)];
#pragma unroll
      for (int t = 0; t < 4; ++t) {
        float v_[4];
        *(float4*)v_ = *(const float4*)&vsh[(cg << 6) + (jg << 2) + t][qq << 2];
#pragma unroll
        for (int u = 0; u < 4; ++u) o[u] = fmaf(pv[t], v_[u], o[u]);
      }
    }
#pragma unroll
    for (int off = 16; off <= 32; off <<= 1) {
#pragma unroll
      for (int u = 0; u < 4; ++u) o[u] += __shfl_xor(o[u], off);
    }
    if (lane < 16) {
      float ov[4];
#pragma unroll
      for (int u = 0; u < 4; ++u) ov[u] = o[u] * rs;
      *(float4*)&ao[((size_t)b * LSEQ + i) * DMODEL + h * DKH + (qq << 2)] =
          *(float4*)ov;
    }
  }
}

// ---------------------------------------------------------------------------
extern "C" void kernel_launch(void* const* d_in, const int* in_sizes, int n_in,
                              void* d_out, int out_size, void* d_ws, size_t ws_size,
                              hipStream_t stream) {
  const float* q   = (const float*)d_in[0];
  const float* k   = (const float*)d_in[1];
  const float* v   = (const float*)d_in[2];
  const int*  mask = (const int*)d_in[3];
  const float* Wq  = (const float*)d_in[4];
  const float* bq  = (const float*)d_in[5];
  const float* Wk  = (const float*)d_in[6];
  const float* bk  = (const float*)d_in[7];
  const float* Wv  = (const float*)d_in[8];
  const float* bv  = (const float*)d_in[9];
  const float* vp  = (const float*)d_in[10];
  const float* W0  = (const float*)d_in[11];
  const float* b0  = (const float*)d_in[12];
  float* outp = (float*)d_out;

  char* wsb = (char*)d_ws;
  unsigned short* whi = (unsigned short*)(wsb);               // 2 MB
  unsigned short* wlo = (unsigned short*)(wsb + (2u << 20));  // 2 MB
  float* qh = (float*)(wsb + (4u << 20));                     // 2 MB
  float* kT = (float*)(wsb + (6u << 20));                     // 2 MB
  float* vh = (float*)(wsb + (8u << 20));                     // 2 MB
  float* ao = (float*)(wsb + (10u << 20));                    // 2 MB

  prep_w_kernel<<<dim3(16, 16, 4), 256, 0, stream>>>(Wq, Wk, Wv, W0, whi, wlo);
  proj_mfma_kernel<<<dim3(16, 8, 3), 256, 0, stream>>>(q, k, v, whi, wlo,
                                                       bq, bk, bv, qh, kT, vh);
  attn_kernel<<<dim3(32, 8), 1024, 0, stream>>>(qh, kT, vh, mask, vp, ao);
  outproj_mfma_kernel<<<dim3(16, 8), 256, 0, stream>>>(ao, whi, wlo, b0, outp);
}